// Round 22
// baseline (256.751 us; speedup 1.0000x reference)
//
#include <hip/hip_runtime.h>
#include <math.h>

#define EPSF 1e-8f

typedef _Float16 f16x8 __attribute__((ext_vector_type(8)));
typedef float f32x16 __attribute__((ext_vector_type(16)));

#define GLOAD_LDS16(g, l)                                                      \
  __builtin_amdgcn_global_load_lds(                                            \
      (const __attribute__((address_space(1))) unsigned int*)(g),              \
      (__attribute__((address_space(3))) unsigned int*)(l), 16, 0, 0)

#define WAITV(n) asm volatile("s_waitcnt vmcnt(" #n ")" ::: "memory")
#define BAR() __builtin_amdgcn_s_barrier()

__device__ __forceinline__ unsigned int ord_from_float(float f) {
  unsigned int u = __float_as_uint(f);
  return (u & 0x80000000u) ? ~u : (u | 0x80000000u);
}

__device__ __forceinline__ float float_from_ord(unsigned int o) {
  return (o & 0x80000000u) ? __uint_as_float(o & 0x7fffffffu)
                           : __uint_as_float(~o);
}

__device__ __forceinline__ unsigned long long shfl_xor_u64(unsigned long long x, int m) {
  int lo = __shfl_xor((int)(unsigned int)(x & 0xffffffffull), m, 64);
  int hi = __shfl_xor((int)(unsigned int)(x >> 32), m, 64);
  return ((unsigned long long)(unsigned int)hi << 32) | (unsigned int)lo;
}

// ---------------- merged prep kernel (r21-verified) ----------------
// Acat row (stride 2*DP): [hi(log) | lo(log)] (hi deduped; GEMM revisits it).
// Bcat row (stride 3*DP): [hi(tgt) | lo(tgt) | hi(tgt)]. Also s_in, s_st,
// packed-init.
__global__ __launch_bounds__(64) void prep_kernel(
    const float* __restrict__ inp, const float* __restrict__ tgt,
    _Float16* __restrict__ Acat, _Float16* __restrict__ Bcat,
    float* __restrict__ s_in, float* __restrict__ s_st,
    unsigned long long* __restrict__ packed,
    int N, int M, int Npad, int Mpad, int D, int DP) {
  const int r = blockIdx.x;
  const int tid = threadIdx.x;
  const int NC4 = D >> 2;
  float sa = 0.f, sb = 0.f;

  _Float16* const arow = (r < Npad) ? Acat + (size_t)r * (2 * DP) : nullptr;
  _Float16* const brow = (r < Mpad) ? Bcat + (size_t)r * (3 * DP) : nullptr;
  const float4* const ain = (const float4*)(inp + (size_t)r * D);
  const float4* const bin = (const float4*)(tgt + (size_t)r * D);

  for (int c = tid; c < NC4; c += 64) {
    if (arow) {
      float4 v = (r < N) ? ain[c] : make_float4(0.f, 0.f, 0.f, 0.f);
      float xs[4] = {v.x, v.y, v.z, v.w};
      #pragma unroll
      for (int e = 0; e < 4; ++e) {
        float x = xs[e];
        sa += x;
        float lg = (r < N) ? logf(x + EPSF) : 0.f;
        _Float16 h = (_Float16)lg;
        _Float16 l = (_Float16)(lg - (float)h);
        int d = c * 4 + e;
        arow[d] = h;
        arow[DP + d] = l;
      }
    }
    if (brow) {
      float4 v = (r < M) ? bin[c] : make_float4(0.f, 0.f, 0.f, 0.f);
      float xs[4] = {v.x, v.y, v.z, v.w};
      #pragma unroll
      for (int e = 0; e < 4; ++e) {
        float x = xs[e];
        if (x > 1.0f)
          sb += x * logf(x) - x + 0.5f * logf(6.283185307179586f * x);
        _Float16 h = (_Float16)x;
        _Float16 l = (_Float16)(x - (float)h);
        int d = c * 4 + e;
        brow[d] = h;
        brow[DP + d] = l;
        brow[2 * DP + d] = h;
      }
    }
  }
  for (int d = (NC4 << 2) + tid; d < D; d += 64) {
    if (arow) {
      float x = (r < N) ? inp[(size_t)r * D + d] : 0.f;
      sa += x;
      float lg = (r < N) ? logf(x + EPSF) : 0.f;
      _Float16 h = (_Float16)lg;
      _Float16 l = (_Float16)(lg - (float)h);
      arow[d] = h; arow[DP + d] = l;
    }
    if (brow) {
      float x = (r < M) ? tgt[(size_t)r * D + d] : 0.f;
      if (x > 1.0f)
        sb += x * logf(x) - x + 0.5f * logf(6.283185307179586f * x);
      _Float16 h = (_Float16)x;
      _Float16 l = (_Float16)(x - (float)h);
      brow[d] = h; brow[DP + d] = l; brow[2 * DP + d] = h;
    }
  }
  for (int d = D + tid; d < DP; d += 64) {
    if (arow) { arow[d] = (_Float16)0.f; arow[DP + d] = (_Float16)0.f; }
    if (brow) { brow[d] = (_Float16)0.f; brow[DP + d] = (_Float16)0.f; brow[2 * DP + d] = (_Float16)0.f; }
  }

  #pragma unroll
  for (int m = 1; m < 64; m <<= 1) {
    sa += __shfl_xor(sa, m, 64);
    sb += __shfl_xor(sb, m, 64);
  }
  if (tid == 0) {
    if (r < N) { s_in[r] = sa; packed[r] = ~0ull; }
    if (r < M) s_st[r] = sb;
  }
}

// ---------------- MFMA pair-min kernel: 256x256, 16 waves, BK=64, 32x32x16 ----
// r21 structure (16 waves of 64x64, 4 waves/SIMD, BK=64, 2 LDS bufs 128 KiB,
// WAITV(0)+BAR/step, 8-slot swizzle, deduped A walk) with the wave tile
// decomposed as 2x2 tiles of 32x32 via mfma_f32_32x32x16_f16: 16 MFMA/step
// (vs 32) at the faster 32x32 rate (m06: 2382 vs 2075 TF), same 16 ds_reads.
// A/B frag: row|col = lane&31, k = (lane>>5)*8+e (extension of the verified
// 16x16 pattern). C/D: col=lane&31, row=(reg&3)+8*(reg>>2)+4*(lane>>5)
// [m74/m101-verified].
#define BT 256
#define UNITH 16384  // halves per (buf,op) unit: 256 rows x 64 halves = 32 KB

__global__ __launch_bounds__(1024) void mfma_pair_min_kernel(
    const _Float16* __restrict__ Acat, const _Float16* __restrict__ Bcat,
    const float* __restrict__ s_st, unsigned long long* __restrict__ packed,
    int N, int M, int DP, int gx) {
  extern __shared__ __align__(16) _Float16 smem[];  // 4 * UNITH = 128 KiB
  const int t = threadIdx.x;
  const int lane = t & 63;
  const int wid = t >> 6;   // 0..15
  const int wr = wid >> 2;  // 0..3 -> 64 output rows each
  const int wc = wid & 3;   // 0..3 -> 64 output cols each
  const int KPA_A = 2 * DP;
  const int KPA_B = 3 * DP;

  // XCD chunking + column-major traversal inside each chunk (round-6 verified)
  const int nwg = gridDim.x;
  const int q8 = nwg >> 3;
  const int xcd = blockIdx.x & 7;
  const int i8 = blockIdx.x >> 3;
  int brow, bcol;
  if (q8 % gx == 0) {
    int bh = q8 / gx;
    brow = xcd * bh + i8 % bh;
    bcol = i8 / bh;
  } else {
    int wg = xcd * q8 + i8;
    brow = wg / gx;
    bcol = wg % gx;
  }
  const int row0 = brow * BT;
  const int col0 = bcol * BT;

  f32x16 acc[2][2] = {};

  // Staging (verified r20/r21): wave wid owns rows [wid*16,+16); 2 gload_lds
  // per operand (8 rows x 128 B). LDS dest linear (lane -> row l>>3, slot
  // l&7); global source slot pre-swizzled: gs = (lane&7)^(lane>>3)
  // => LDS(r,s) = global(r, s^(r&7)).
  const int srow = lane >> 3;
  const int gs = (lane & 7) ^ (lane >> 3);
  const _Float16* const aB0 = Acat + (size_t)(row0 + wid * 16 + srow) * KPA_A + gs * 8;
  const _Float16* const aB1 = aB0 + (size_t)8 * KPA_A;
  const _Float16* const bB0 = Bcat + (size_t)(col0 + wid * 16 + srow) * KPA_B + gs * 8;
  const _Float16* const bB1 = bB0 + (size_t)8 * KPA_B;
  const int SEG = DP >> 6;  // K-steps per segment (3 for D=180)

#define STAGE(buf_, kt_)                                                       \
  do {                                                                         \
    const int ka_ = ((kt_) < SEG ? (kt_) : (kt_) - SEG) * 64;                  \
    const int kb_ = (kt_) * 64;                                                \
    _Float16* dA_ = smem + (buf_) * 2 * UNITH + wid * 1024;                    \
    _Float16* dB_ = dA_ + UNITH;                                               \
    GLOAD_LDS16(aB0 + ka_, dA_);                                               \
    GLOAD_LDS16(aB1 + ka_, dA_ + 512);                                         \
    GLOAD_LDS16(bB0 + kb_, dB_);                                               \
    GLOAD_LDS16(bB1 + kb_, dB_ + 512);                                         \
  } while (0)

  const int l31 = lane & 31;
  const int h5 = lane >> 5;   // 0..1
  // read slot for k-chunk c (k = c*16 + h5*8 + e), row r: slot = (c*2+h5)^(r&7)
  // r&7 == l31&7 == lane&7 for all frag rows (i*32 doesn't affect low 3 bits).
  const int sw = lane & 7;

#define COMPUTE(buf_)                                                          \
  do {                                                                         \
    const _Float16* pA_ = smem + (buf_) * 2 * UNITH;                           \
    const _Float16* pB_ = pA_ + UNITH;                                         \
    _Pragma("unroll")                                                          \
    for (int c = 0; c < 4; ++c) {                                              \
      const int sc_ = (c * 2 + h5) ^ sw;                                       \
      f16x8 af[2], bf[2];                                                      \
      _Pragma("unroll")                                                        \
      for (int i = 0; i < 2; ++i)                                              \
        af[i] = *(const f16x8*)(pA_ + (wr * 64 + i * 32 + l31) * 64 + sc_ * 8); \
      _Pragma("unroll")                                                        \
      for (int j = 0; j < 2; ++j)                                              \
        bf[j] = *(const f16x8*)(pB_ + (wc * 64 + j * 32 + l31) * 64 + sc_ * 8); \
      __builtin_amdgcn_s_setprio(1);                                           \
      _Pragma("unroll")                                                        \
      for (int i = 0; i < 2; ++i)                                              \
        _Pragma("unroll")                                                      \
        for (int j = 0; j < 2; ++j)                                            \
          acc[i][j] = __builtin_amdgcn_mfma_f32_32x32x16_f16(af[i], bf[j],     \
                                                             acc[i][j], 0, 0, 0); \
      __builtin_amdgcn_s_setprio(0);                                           \
    }                                                                          \
  } while (0)

  const int NT = 3 * SEG;  // 9 for D=180

  STAGE(0, 0);
  WAITV(0);
  BAR();
  for (int kt = 0; kt < NT - 1; ++kt) {
    STAGE((kt + 1) & 1, kt + 1);  // issue next-step loads first
    COMPUTE(kt & 1);
    WAITV(0);
    BAR();
  }
  COMPUTE((NT - 1) & 1);

#undef STAGE
#undef COMPUTE

  // ---- fused min/argmin epilogue ----
  // C/D 32x32 frag: col = lane&31, row = (reg&3)+8*(reg>>2)+4*(lane>>5)
  // [m74/m101-verified]. Lanes sharing a row = the 32 lanes with equal h5;
  // reduce via shfl_xor m=1..16 (stays within the 32-lane half).
  float stv[2];
  #pragma unroll
  for (int j = 0; j < 2; ++j) {
    int gj = col0 + wc * 64 + j * 32 + l31;
    stv[j] = (gj < M) ? s_st[gj] : __builtin_inff();
  }
  #pragma unroll
  for (int i = 0; i < 2; ++i) {
    #pragma unroll
    for (int reg = 0; reg < 16; ++reg) {
      int grow = row0 + wr * 64 + i * 32 + (reg & 3) + 8 * (reg >> 2) + 4 * h5;
      unsigned long long bst = ~0ull;
      #pragma unroll
      for (int j = 0; j < 2; ++j) {
        int gj = col0 + wc * 64 + j * 32 + l31;
        float val = stv[j] - acc[i][j][reg];
        unsigned long long p =
            ((unsigned long long)ord_from_float(val) << 32) | (unsigned int)gj;
        if (p < bst) bst = p;
      }
      #pragma unroll
      for (int mm = 1; mm < 32; mm <<= 1) {
        unsigned long long o = shfl_xor_u64(bst, mm);
        if (o < bst) bst = o;
      }
      if (l31 == 0 && grow < N) atomicMin(&packed[grow], bst);
    }
  }
}

// ---------------- reduce (with last-block final fold, r21-verified) ----------------
__global__ __launch_bounds__(256) void reduce_kernel(
    const unsigned long long* __restrict__ packed,
    const float* __restrict__ s_in, float* __restrict__ out,
    unsigned long long* __restrict__ sumbuf, int N, int nblocks) {
  int i = blockIdx.x * 256 + threadIdx.x;
  double local = 0.0;
  if (i < N) {
    unsigned long long p = packed[i];
    out[1 + i] = (float)(unsigned int)(p & 0xffffffffull);
    float val = float_from_ord((unsigned int)(p >> 32));
    local = (double)(s_in[i] + val);
  }
  __shared__ double sh[256];
  sh[threadIdx.x] = local;
  __syncthreads();
  for (int o = 128; o > 0; o >>= 1) {
    if (threadIdx.x < o) sh[threadIdx.x] += sh[threadIdx.x + o];
    __syncthreads();
  }
  if (threadIdx.x == 0) {
    long long q = __double2ll_rn(sh[0] * 1048576.0);  // fixed-point: deterministic
    atomicAdd(&sumbuf[0], (unsigned long long)q);
    __threadfence();
    unsigned long long done = atomicAdd(&sumbuf[1], 1ull);
    if (done == (unsigned long long)(nblocks - 1)) {
      unsigned long long s = atomicAdd(&sumbuf[0], 0ull);  // atomic read
      out[0] = (float)(((double)(long long)s / 1048576.0) / (double)N);
    }
  }
}

extern "C" void kernel_launch(void* const* d_in, const int* in_sizes, int n_in,
                              void* d_out, int out_size, void* d_ws, size_t ws_size,
                              hipStream_t stream) {
  const float* inp = (const float*)d_in[0];
  const float* tgt = (const float*)d_in[1];
  float* out = (float*)d_out;

  int N = out_size - 1;  // outputs: [loss scalar, match[N]]
  int D = in_sizes[0] / N;
  int M = in_sizes[1] / D;

  int Npad = ((N + BT - 1) / BT) * BT;
  int Mpad = ((M + BT - 1) / BT) * BT;
  int DP = ((D + 31) / 32) * 32;  // 192 for D=180
  int gx = Mpad / BT, gy = Npad / BT;

  // Workspace layout. CRITICAL (r17 lesson): Acat/Bcat must be 256-B aligned.
  char* ws = (char*)d_ws;
  size_t off = 0;
  float* s_in = (float*)(ws + off); off += (size_t)N * 4;
  float* s_st = (float*)(ws + off); off += (size_t)M * 4;
  off = (off + 15) & ~(size_t)15;
  unsigned long long* packed = (unsigned long long*)(ws + off); off += (size_t)N * 8;
  off = (off + 15) & ~(size_t)15;
  unsigned long long* sumbuf = (unsigned long long*)(ws + off); off += 16;
  off = (off + 255) & ~(size_t)255;
  _Float16* Acat = (_Float16*)(ws + off); off += (size_t)Npad * (2 * DP) * 2;
  off = (off + 255) & ~(size_t)255;
  _Float16* Bcat = (_Float16*)(ws + off); off += (size_t)Mpad * (3 * DP) * 2;

  hipMemsetAsync(sumbuf, 0, 16, stream);  // sum + completion counter

  int pgrid = Npad > Mpad ? Npad : Mpad;
  prep_kernel<<<pgrid, 64, 0, stream>>>(inp, tgt, Acat, Bcat, s_in, s_st,
                                        packed, N, M, Npad, Mpad, D, DP);

  const int ldsBytes = 4 * UNITH * 2;  // 128 KiB
  hipFuncSetAttribute((const void*)mfma_pair_min_kernel,
                      hipFuncAttributeMaxDynamicSharedMemorySize, ldsBytes);
  mfma_pair_min_kernel<<<gx * gy, 1024, ldsBytes, stream>>>(
      Acat, Bcat, s_st, packed, N, M, DP, gx);

  int rblocks = (N + 255) / 256;
  reduce_kernel<<<rblocks, 256, 0, stream>>>(packed, s_in, out, sumbuf, N,
                                             rblocks);
}

// Round 23
// 177.328 us; speedup vs baseline: 1.4479x; 1.4479x over previous
//
#include <hip/hip_runtime.h>
#include <math.h>

#define EPSF 1e-8f

typedef _Float16 f16x8 __attribute__((ext_vector_type(8)));
typedef float f32x4 __attribute__((ext_vector_type(4)));

#define GLOAD_LDS16(g, l)                                                      \
  __builtin_amdgcn_global_load_lds(                                            \
      (const __attribute__((address_space(1))) unsigned int*)(g),              \
      (__attribute__((address_space(3))) unsigned int*)(l), 16, 0, 0)

#define WAITV(n) asm volatile("s_waitcnt vmcnt(" #n ")" ::: "memory")
#define BAR() __builtin_amdgcn_s_barrier()

__device__ __forceinline__ unsigned int ord_from_float(float f) {
  unsigned int u = __float_as_uint(f);
  return (u & 0x80000000u) ? ~u : (u | 0x80000000u);
}

__device__ __forceinline__ float float_from_ord(unsigned int o) {
  return (o & 0x80000000u) ? __uint_as_float(o & 0x7fffffffu)
                           : __uint_as_float(~o);
}

__device__ __forceinline__ unsigned long long shfl_xor_u64(unsigned long long x, int m) {
  int lo = __shfl_xor((int)(unsigned int)(x & 0xffffffffull), m, 64);
  int hi = __shfl_xor((int)(unsigned int)(x >> 32), m, 64);
  return ((unsigned long long)(unsigned int)hi << 32) | (unsigned int)lo;
}

// ---------------- merged prep kernel ----------------
// Acat row (stride 2*DP): [hi(log) @0 | lo(log) @DP]  (hi seg deduped — the
// GEMM revisits it), zeros in [D,DP). Bcat row (stride 3*DP):
// [hi(tgt) | lo(tgt) | hi(tgt)]. Also s_in, s_st, packed-init.
__global__ __launch_bounds__(64) void prep_kernel(
    const float* __restrict__ inp, const float* __restrict__ tgt,
    _Float16* __restrict__ Acat, _Float16* __restrict__ Bcat,
    float* __restrict__ s_in, float* __restrict__ s_st,
    unsigned long long* __restrict__ packed,
    int N, int M, int Npad, int Mpad, int D, int DP) {
  const int r = blockIdx.x;
  const int tid = threadIdx.x;
  const int NC4 = D >> 2;
  float sa = 0.f, sb = 0.f;

  _Float16* const arow = (r < Npad) ? Acat + (size_t)r * (2 * DP) : nullptr;
  _Float16* const brow = (r < Mpad) ? Bcat + (size_t)r * (3 * DP) : nullptr;
  const float4* const ain = (const float4*)(inp + (size_t)r * D);
  const float4* const bin = (const float4*)(tgt + (size_t)r * D);

  for (int c = tid; c < NC4; c += 64) {
    if (arow) {
      float4 v = (r < N) ? ain[c] : make_float4(0.f, 0.f, 0.f, 0.f);
      float xs[4] = {v.x, v.y, v.z, v.w};
      #pragma unroll
      for (int e = 0; e < 4; ++e) {
        float x = xs[e];
        sa += x;
        float lg = (r < N) ? logf(x + EPSF) : 0.f;
        _Float16 h = (_Float16)lg;
        _Float16 l = (_Float16)(lg - (float)h);
        int d = c * 4 + e;
        arow[d] = h;
        arow[DP + d] = l;
      }
    }
    if (brow) {
      float4 v = (r < M) ? bin[c] : make_float4(0.f, 0.f, 0.f, 0.f);
      float xs[4] = {v.x, v.y, v.z, v.w};
      #pragma unroll
      for (int e = 0; e < 4; ++e) {
        float x = xs[e];
        if (x > 1.0f)
          sb += x * logf(x) - x + 0.5f * logf(6.283185307179586f * x);
        _Float16 h = (_Float16)x;
        _Float16 l = (_Float16)(x - (float)h);
        int d = c * 4 + e;
        brow[d] = h;
        brow[DP + d] = l;
        brow[2 * DP + d] = h;
      }
    }
  }
  for (int d = (NC4 << 2) + tid; d < D; d += 64) {
    if (arow) {
      float x = (r < N) ? inp[(size_t)r * D + d] : 0.f;
      sa += x;
      float lg = (r < N) ? logf(x + EPSF) : 0.f;
      _Float16 h = (_Float16)lg;
      _Float16 l = (_Float16)(lg - (float)h);
      arow[d] = h; arow[DP + d] = l;
    }
    if (brow) {
      float x = (r < M) ? tgt[(size_t)r * D + d] : 0.f;
      if (x > 1.0f)
        sb += x * logf(x) - x + 0.5f * logf(6.283185307179586f * x);
      _Float16 h = (_Float16)x;
      _Float16 l = (_Float16)(x - (float)h);
      brow[d] = h; brow[DP + d] = l; brow[2 * DP + d] = h;
    }
  }
  for (int d = D + tid; d < DP; d += 64) {
    if (arow) { arow[d] = (_Float16)0.f; arow[DP + d] = (_Float16)0.f; }
    if (brow) { brow[d] = (_Float16)0.f; brow[DP + d] = (_Float16)0.f; brow[2 * DP + d] = (_Float16)0.f; }
  }

  #pragma unroll
  for (int m = 1; m < 64; m <<= 1) {
    sa += __shfl_xor(sa, m, 64);
    sb += __shfl_xor(sb, m, 64);
  }
  if (tid == 0) {
    if (r < N) { s_in[r] = sa; packed[r] = ~0ull; }
    if (r < M) s_st[r] = sb;
  }
}

// ---------------- MFMA pair-min kernel: 256x256, 16 waves, BK=64 ----------------
// r21-verified optimum: 16 waves of 64x64 (4 waves/SIMD), BK=64, 2 LDS bufs
// 128 KiB, WAITV(0)+BAR per step, 8-slot swizzle (16-row frag span -> 2-way
// bank aliasing = free; the 32x32 variant's 32-row span = 4-way = +57% — r22).
// A walked with deduped [hi|lo] layout: ka = (kt<SEG ? kt : kt-SEG)*64.
#define BT 256
#define UNITH 16384  // halves per (buf,op) unit: 256 rows x 64 halves = 32 KB

__global__ __launch_bounds__(1024) void mfma_pair_min_kernel(
    const _Float16* __restrict__ Acat, const _Float16* __restrict__ Bcat,
    const float* __restrict__ s_st, unsigned long long* __restrict__ packed,
    int N, int M, int DP, int gx) {
  extern __shared__ __align__(16) _Float16 smem[];  // 4 * UNITH = 128 KiB
  const int t = threadIdx.x;
  const int lane = t & 63;
  const int wid = t >> 6;   // 0..15
  const int wr = wid >> 2;  // 0..3 -> 64 output rows each
  const int wc = wid & 3;   // 0..3 -> 64 output cols each
  const int KPA_A = 2 * DP;
  const int KPA_B = 3 * DP;

  // XCD chunking + column-major traversal inside each chunk (round-6 verified)
  const int nwg = gridDim.x;
  const int q8 = nwg >> 3;
  const int xcd = blockIdx.x & 7;
  const int i8 = blockIdx.x >> 3;
  int brow, bcol;
  if (q8 % gx == 0) {
    int bh = q8 / gx;
    brow = xcd * bh + i8 % bh;
    bcol = i8 / bh;
  } else {
    int wg = xcd * q8 + i8;
    brow = wg / gx;
    bcol = wg % gx;
  }
  const int row0 = brow * BT;
  const int col0 = bcol * BT;

  f32x4 acc[4][4] = {};

  // Staging (BK=64, verified r20/r21): wave wid owns rows [wid*16,+16);
  // 2 gload_lds per operand (8 rows x 128 B). LDS dest linear (lane -> row
  // l>>3, slot l&7); global source slot pre-swizzled: gs = (lane&7)^(lane>>3)
  // => LDS(r,s) = global(r, s^(r&7)).
  const int srow = lane >> 3;
  const int gs = (lane & 7) ^ (lane >> 3);
  const _Float16* const aB0 = Acat + (size_t)(row0 + wid * 16 + srow) * KPA_A + gs * 8;
  const _Float16* const aB1 = aB0 + (size_t)8 * KPA_A;
  const _Float16* const bB0 = Bcat + (size_t)(col0 + wid * 16 + srow) * KPA_B + gs * 8;
  const _Float16* const bB1 = bB0 + (size_t)8 * KPA_B;
  const int SEG = DP >> 6;  // K-steps per segment (3 for D=180)

#define STAGE(buf_, kt_)                                                       \
  do {                                                                         \
    const int ka_ = ((kt_) < SEG ? (kt_) : (kt_) - SEG) * 64;                  \
    const int kb_ = (kt_) * 64;                                                \
    _Float16* dA_ = smem + (buf_) * 2 * UNITH + wid * 1024;                    \
    _Float16* dB_ = dA_ + UNITH;                                               \
    GLOAD_LDS16(aB0 + ka_, dA_);                                               \
    GLOAD_LDS16(aB1 + ka_, dA_ + 512);                                         \
    GLOAD_LDS16(bB0 + kb_, dB_);                                               \
    GLOAD_LDS16(bB1 + kb_, dB_ + 512);                                         \
  } while (0)

  const int rl = lane & 15;
  const int qq = lane >> 4;
  const int s0 = (0 * 4 + qq) ^ (rl & 7);  // chunk-0 swizzled slot
  const int s1 = (1 * 4 + qq) ^ (rl & 7);  // chunk-1

#define COMPUTE(buf_)                                                          \
  do {                                                                         \
    const _Float16* pA_ = smem + (buf_) * 2 * UNITH;                           \
    const _Float16* pB_ = pA_ + UNITH;                                         \
    f16x8 af[4], bf[4];                                                        \
    _Pragma("unroll")                                                          \
    for (int m = 0; m < 4; ++m)                                                \
      af[m] = *(const f16x8*)(pA_ + (wr * 64 + m * 16 + rl) * 64 + s0 * 8);    \
    _Pragma("unroll")                                                          \
    for (int n = 0; n < 4; ++n)                                                \
      bf[n] = *(const f16x8*)(pB_ + (wc * 64 + n * 16 + rl) * 64 + s0 * 8);    \
    __builtin_amdgcn_s_setprio(1);                                             \
    _Pragma("unroll")                                                          \
    for (int m = 0; m < 4; ++m)                                                \
      _Pragma("unroll")                                                        \
      for (int n = 0; n < 4; ++n)                                              \
        acc[m][n] = __builtin_amdgcn_mfma_f32_16x16x32_f16(af[m], bf[n],       \
                                                           acc[m][n], 0, 0, 0); \
    __builtin_amdgcn_s_setprio(0);                                             \
    _Pragma("unroll")                                                          \
    for (int m = 0; m < 4; ++m)                                                \
      af[m] = *(const f16x8*)(pA_ + (wr * 64 + m * 16 + rl) * 64 + s1 * 8);    \
    _Pragma("unroll")                                                          \
    for (int n = 0; n < 4; ++n)                                                \
      bf[n] = *(const f16x8*)(pB_ + (wc * 64 + n * 16 + rl) * 64 + s1 * 8);    \
    __builtin_amdgcn_s_setprio(1);                                             \
    _Pragma("unroll")                                                          \
    for (int m = 0; m < 4; ++m)                                                \
      _Pragma("unroll")                                                        \
      for (int n = 0; n < 4; ++n)                                              \
        acc[m][n] = __builtin_amdgcn_mfma_f32_16x16x32_f16(af[m], bf[n],       \
                                                           acc[m][n], 0, 0, 0); \
    __builtin_amdgcn_s_setprio(0);                                             \
  } while (0)

  const int NT = 3 * SEG;  // 9 for D=180

  STAGE(0, 0);
  WAITV(0);
  BAR();
  for (int kt = 0; kt < NT - 1; ++kt) {
    STAGE((kt + 1) & 1, kt + 1);  // issue next-step loads first
    COMPUTE(kt & 1);
    WAITV(0);
    BAR();
  }
  COMPUTE((NT - 1) & 1);

#undef STAGE
#undef COMPUTE

  // ---- fused min/argmin epilogue (atomicMin, verified) ----
  // C/D frag: col = lane&15, row = (lane>>4)*4 + reg   [guide §3, m89-verified]
  float stv[4];
  #pragma unroll
  for (int n = 0; n < 4; ++n) {
    int gj = col0 + wc * 64 + n * 16 + rl;
    stv[n] = (gj < M) ? s_st[gj] : __builtin_inff();
  }
  #pragma unroll
  for (int m = 0; m < 4; ++m) {
    #pragma unroll
    for (int g = 0; g < 4; ++g) {
      int grow = row0 + wr * 64 + m * 16 + qq * 4 + g;
      unsigned long long bst = ~0ull;
      #pragma unroll
      for (int n = 0; n < 4; ++n) {
        int gj = col0 + wc * 64 + n * 16 + rl;
        float val = stv[n] - acc[m][n][g];
        unsigned long long p =
            ((unsigned long long)ord_from_float(val) << 32) | (unsigned int)gj;
        if (p < bst) bst = p;
      }
      #pragma unroll
      for (int mm = 1; mm < 16; mm <<= 1) {
        unsigned long long o = shfl_xor_u64(bst, mm);
        if (o < bst) bst = o;
      }
      if (rl == 0 && grow < N) atomicMin(&packed[grow], bst);
    }
  }
}

// ---------------- reduce (with last-block final fold) ----------------
// sumbuf[0]: fixed-point (x2^20) integer sum — order-independent, so the
// completion-counter pattern stays deterministic. sumbuf[1]: block counter.
__global__ __launch_bounds__(256) void reduce_kernel(
    const unsigned long long* __restrict__ packed,
    const float* __restrict__ s_in, float* __restrict__ out,
    unsigned long long* __restrict__ sumbuf, int N, int nblocks) {
  int i = blockIdx.x * 256 + threadIdx.x;
  double local = 0.0;
  if (i < N) {
    unsigned long long p = packed[i];
    out[1 + i] = (float)(unsigned int)(p & 0xffffffffull);
    float val = float_from_ord((unsigned int)(p >> 32));
    local = (double)(s_in[i] + val);
  }
  __shared__ double sh[256];
  sh[threadIdx.x] = local;
  __syncthreads();
  for (int o = 128; o > 0; o >>= 1) {
    if (threadIdx.x < o) sh[threadIdx.x] += sh[threadIdx.x + o];
    __syncthreads();
  }
  if (threadIdx.x == 0) {
    long long q = __double2ll_rn(sh[0] * 1048576.0);
    atomicAdd(&sumbuf[0], (unsigned long long)q);
    __threadfence();  // make the add visible before signaling completion
    unsigned long long done = atomicAdd(&sumbuf[1], 1ull);
    if (done == (unsigned long long)(nblocks - 1)) {
      unsigned long long s = atomicAdd(&sumbuf[0], 0ull);  // atomic read
      out[0] = (float)(((double)(long long)s / 1048576.0) / (double)N);
    }
  }
}

extern "C" void kernel_launch(void* const* d_in, const int* in_sizes, int n_in,
                              void* d_out, int out_size, void* d_ws, size_t ws_size,
                              hipStream_t stream) {
  const float* inp = (const float*)d_in[0];
  const float* tgt = (const float*)d_in[1];
  float* out = (float*)d_out;

  int N = out_size - 1;  // outputs: [loss scalar, match[N]]
  int D = in_sizes[0] / N;
  int M = in_sizes[1] / D;

  int Npad = ((N + BT - 1) / BT) * BT;
  int Mpad = ((M + BT - 1) / BT) * BT;
  int DP = ((D + 31) / 32) * 32;  // 192 for D=180
  int gx = Mpad / BT, gy = Npad / BT;

  // Workspace layout. CRITICAL (r17 lesson): Acat/Bcat must be 256-B aligned.
  char* ws = (char*)d_ws;
  size_t off = 0;
  float* s_in = (float*)(ws + off); off += (size_t)N * 4;
  float* s_st = (float*)(ws + off); off += (size_t)M * 4;
  off = (off + 15) & ~(size_t)15;
  unsigned long long* packed = (unsigned long long*)(ws + off); off += (size_t)N * 8;
  off = (off + 15) & ~(size_t)15;
  unsigned long long* sumbuf = (unsigned long long*)(ws + off); off += 16;
  off = (off + 255) & ~(size_t)255;
  _Float16* Acat = (_Float16*)(ws + off); off += (size_t)Npad * (2 * DP) * 2;
  off = (off + 255) & ~(size_t)255;
  _Float16* Bcat = (_Float16*)(ws + off); off += (size_t)Mpad * (3 * DP) * 2;

  hipMemsetAsync(sumbuf, 0, 16, stream);  // sum + completion counter

  int pgrid = Npad > Mpad ? Npad : Mpad;
  prep_kernel<<<pgrid, 64, 0, stream>>>(inp, tgt, Acat, Bcat, s_in, s_st,
                                        packed, N, M, Npad, Mpad, D, DP);

  const int ldsBytes = 4 * UNITH * 2;  // 128 KiB
  hipFuncSetAttribute((const void*)mfma_pair_min_kernel,
                      hipFuncAttributeMaxDynamicSharedMemorySize, ldsBytes);
  mfma_pair_min_kernel<<<gx * gy, 1024, ldsBytes, stream>>>(
      Acat, Bcat, s_st, packed, N, M, DP, gx);

  int rblocks = (N + 255) / 256;
  reduce_kernel<<<rblocks, 256, 0, stream>>>(packed, s_in, out, sumbuf, N,
                                             rblocks);
}